// Round 2
// baseline (495.570 us; speedup 1.0000x reference)
//
#include <hip/hip_runtime.h>
#include <hip/hip_bf16.h>

#define Sdim 4096
#define Ndim 32
#define Hdim 512
#define Mdim (Sdim * Ndim)

#define BM 64
#define BN 512
#define BK 64

typedef __bf16 bf16x8 __attribute__((ext_vector_type(8)));
typedef float f32x4 __attribute__((ext_vector_type(4)));
typedef unsigned short ushort8v __attribute__((ext_vector_type(8)));

__device__ __forceinline__ void load_lds16(const void* g, void* l) {
    __builtin_amdgcn_global_load_lds(
        (const __attribute__((address_space(1))) void*)g,
        (__attribute__((address_space(3))) void*)l, 16, 0, 0);
}

__device__ __forceinline__ float ftanh(float x) {
    float e = __expf(2.f * x);
    return 1.f - 2.f / (e + 1.f);
}

// ---------------- bias[n][c] = hidden[n]·Ww[c] + Wb[c] + Ub[c]
__global__ __launch_bounds__(256) void k_prep_bias(
    const float* __restrict__ hidden, const float* __restrict__ Ww,
    const float* __restrict__ Wb, const float* __restrict__ Ubias,
    float* __restrict__ bias) {
    const int t = threadIdx.x, w = t >> 6, lane = t & 63;
    const int cc = blockIdx.x * 4 + w;
    const float4 w0 = *(const float4*)(Ww + (size_t)cc * Hdim + lane * 8);
    const float4 w1 = *(const float4*)(Ww + (size_t)cc * Hdim + lane * 8 + 4);
    const float wb = Wb[cc] + Ubias[cc];
    for (int n = 0; n < Ndim; ++n) {
        const float4 h0 = *(const float4*)(hidden + n * Hdim + lane * 8);
        const float4 h1 = *(const float4*)(hidden + n * Hdim + lane * 8 + 4);
        float p = w0.x * h0.x + w0.y * h0.y + w0.z * h0.z + w0.w * h0.w +
                  w1.x * h1.x + w1.y * h1.y + w1.z * h1.z + w1.w * h1.w;
        p += __shfl_xor(p, 1);  p += __shfl_xor(p, 2);
        p += __shfl_xor(p, 4);  p += __shfl_xor(p, 8);
        p += __shfl_xor(p, 16); p += __shfl_xor(p, 32);
        if (lane == 0) bias[n * Hdim + cc] = p + wb;
    }
}

// ---------------- U_w fp32 -> bf16 (packed cvt)
__global__ __launch_bounds__(256) void k_cvt(
    const float* __restrict__ src, unsigned short* __restrict__ dst) {
    const int i = blockIdx.x * 256 + threadIdx.x;
    float4 v = ((const float4*)src)[i];
    union { __hip_bfloat162 h[2]; ushort4 u; } r;
    r.h[0] = __float22bfloat162_rn(make_float2(v.x, v.y));
    r.h[1] = __float22bfloat162_rn(make_float2(v.z, v.w));
    ((ushort4*)dst)[i] = r.u;
}

// ---------------- fused score: BM=64 rows x BN=512 (all cols), BK=64.
// One block owns full output rows -> writes FINAL score (no partials).
// A cvt halved vs colblk-split; A prefetch 2-deep; counted vmcnt(2).
#define GS_STEP(KK, A0, A1)                                                    \
    {                                                                          \
        asm volatile("" ::: "memory");                                         \
        __builtin_amdgcn_s_barrier();                                          \
        asm volatile("" ::: "memory");                                         \
        __builtin_amdgcn_sched_barrier(0);                                     \
        _Pragma("unroll") for (int g = 0; g < 8; ++g)                          \
            load_lds16(bsrc + (size_t)g * 8 * Hdim + (KK)*BK,                  \
                       bdst + g * 8 * BK);                                     \
        asm volatile("" ::: "memory");                                         \
        __builtin_amdgcn_sched_barrier(0);                                     \
        union { __hip_bfloat162 h[4]; ushort8v v; } pk;                        \
        pk.h[0] = __float22bfloat162_rn(make_float2(A0.x, A0.y));              \
        pk.h[1] = __float22bfloat162_rn(make_float2(A0.z, A0.w));              \
        pk.h[2] = __float22bfloat162_rn(make_float2(A1.x, A1.y));              \
        pk.h[3] = __float22bfloat162_rn(make_float2(A1.z, A1.w));              \
        *(ushort8v*)awr = pk.v;                                                \
        {                                                                      \
            const int kn = ((KK) + 2 < 8) ? (KK) + 2 : 7;                      \
            A0 = *(const float4*)(abase + kn * 64);                            \
            A1 = *(const float4*)(abase + kn * 64 + 4);                        \
        }                                                                      \
        asm volatile("" ::: "memory");                                         \
        __builtin_amdgcn_sched_barrier(0);                                     \
        asm volatile("s_waitcnt vmcnt(2) lgkmcnt(0)" ::: "memory");            \
        __builtin_amdgcn_s_barrier();                                          \
        asm volatile("" ::: "memory");                                         \
        __builtin_amdgcn_sched_barrier(0);                                     \
        _Pragma("unroll 1") for (int h = 0; h < 2; ++h) {                      \
            bf16x8 af[4], bfr[4];                                              \
            const int ch = (h << 2) | q;                                       \
            _Pragma("unroll") for (int mi = 0; mi < 4; ++mi)                   \
                af[mi] = *(const bf16x8*)&Asm[mi * 16 + c][ch * 8];            \
            _Pragma("unroll") for (int ni = 0; ni < 4; ++ni)                   \
                bfr[ni] = *(const bf16x8*)&Bsm[(w * 64 + ni * 16 + c) * BK +   \
                                               ((ch ^ sB) * 8)];               \
            _Pragma("unroll") for (int mi = 0; mi < 4; ++mi)                   \
                _Pragma("unroll") for (int ni = 0; ni < 4; ++ni)               \
                    acc[mi][ni] = __builtin_amdgcn_mfma_f32_16x16x32_bf16(     \
                        af[mi], bfr[ni], acc[mi][ni], 0, 0, 0);                \
        }                                                                      \
    }

__global__ __launch_bounds__(512, 4) void k_gemm_score(
    const float* __restrict__ enc,          // [M, H] fp32
    const unsigned short* __restrict__ Ub,  // [H, H] bf16, row=out col
    const float* __restrict__ bias,         // [N, H]
    const float* __restrict__ vw,           // [H]
    float* __restrict__ scorep) {           // [N, S] final scores
    __shared__ __align__(16) unsigned short Asm[BM][72];  // 144B rows
    __shared__ __align__(16) unsigned short Bsm[BN * BK]; // linear, swizzled
    __shared__ float ssm[8][BM];

    const int t = threadIdx.x;
    const int lane = t & 63;
    const int w = t >> 6;  // wave id = 64-col block
    const int c = lane & 15;
    const int q = lane >> 4;

    const int mBase = blockIdx.x * BM;

    // A staging: thread -> row t>>3, chunk t&7 (8 floats = 32B)
    const float* abase = enc + (size_t)(mBase + (t >> 3)) * Hdim + (t & 7) * 8;
    unsigned short* awr = &Asm[t >> 3][(t & 7) * 8];

    // B staging: per wave 64 cols, 8 lanes/col; source chunk XOR-swizzled
    const int csub = lane >> 3;  // 0..7
    const unsigned short* bsrc = Ub + (size_t)(w * 64 + csub) * Hdim +
                                 ((lane & 7) ^ csub) * 8;
    unsigned short* bdst = Bsm + (w * 64) * BK;

    const int sB = c & 7;  // B un-swizzle (lane const)

    f32x4 acc[4][4];
#pragma unroll
    for (int i = 0; i < 4; ++i)
#pragma unroll
        for (int j = 0; j < 4; ++j) acc[i][j] = (f32x4){0.f, 0.f, 0.f, 0.f};

    // prologue: A(0), A(1) in flight (2-deep)
    float4 aA0 = *(const float4*)(abase + 0);
    float4 aA1 = *(const float4*)(abase + 4);
    float4 aB0 = *(const float4*)(abase + 64);
    float4 aB1 = *(const float4*)(abase + 68);

#pragma unroll 1
    for (int kk = 0; kk < 8; kk += 2) {
        GS_STEP(kk, aA0, aA1);
        GS_STEP(kk + 1, aB0, aB1);
    }
    // keep tail prefetches live: DCE would break the vmcnt(2) count
    asm volatile("" :: "v"(aA0.x), "v"(aA1.x), "v"(aB0.x), "v"(aB1.x));

    // epilogue: score[row] = sum_col v[col]*tanh(acc + bias[n][col])
    float vcol[4];
#pragma unroll
    for (int ni = 0; ni < 4; ++ni) vcol[ni] = vw[w * 64 + ni * 16 + c];

#pragma unroll
    for (int mi = 0; mi < 4; ++mi) {
#pragma unroll
        for (int reg = 0; reg < 4; ++reg) {
            const int rl = mi * 16 + q * 4 + reg;
            const int n = rl & 31;  // mBase % 32 == 0
            float p = 0.f;
#pragma unroll
            for (int ni = 0; ni < 4; ++ni) {
                const int col = w * 64 + ni * 16 + c;
                float e = acc[mi][ni][reg] + bias[n * Hdim + col];
                p += vcol[ni] * ftanh(e);
            }
            p += __shfl_xor(p, 1);
            p += __shfl_xor(p, 2);
            p += __shfl_xor(p, 4);
            p += __shfl_xor(p, 8);
            if (c == 0) ssm[w][rl] = p;
        }
    }
    __syncthreads();
    if (t < BM) {
        const int m = mBase + t;
        const float s = ssm[0][t] + ssm[1][t] + ssm[2][t] + ssm[3][t] +
                        ssm[4][t] + ssm[5][t] + ssm[6][t] + ssm[7][t];
        scorep[(m & 31) * Sdim + (m >> 5)] = s;
    }
}

// ---------------- 1/sum(exp(score)) per n. Scores are O(1): no max-sub
// needed (softmax is shift-invariant; exp cannot overflow here).
__global__ __launch_bounds__(256) void k_sumexp(
    const float* __restrict__ scorep,  // [N][S]
    float* __restrict__ sums) {        // [N] inverse sums
    const int n = blockIdx.x;
    const int t = threadIdx.x;
    const int w = t >> 6;
    const float4* p = (const float4*)(scorep + n * Sdim);
    float s = 0.f;
    for (int i = t; i < Sdim / 4; i += 256) {
        const float4 v = p[i];
        s += __expf(v.x) + __expf(v.y) + __expf(v.z) + __expf(v.w);
    }
#pragma unroll
    for (int o = 32; o > 0; o >>= 1) s += __shfl_xor(s, o);
    __shared__ float red[4];
    if ((t & 63) == 0) red[w] = s;
    __syncthreads();
    if (t == 0) sums[n] = 1.f / (red[0] + red[1] + red[2] + red[3]);
}

// ---------------- fused weights+context: w = exp(score)*inv computed here,
// written to out_w, and used for the weighted enc accumulation.
__global__ __launch_bounds__(512) void k_context(
    const float* __restrict__ enc, const float* __restrict__ scorep,
    const float* __restrict__ sums, float* __restrict__ out_w,
    float* __restrict__ part) {
    const int n = blockIdx.x & 31;
    const int sc = blockIdx.x >> 5;  // 0..15
    const int s0 = sc * 256;
    const int t = threadIdx.x;
    const int g = t >> 6;    // 0..7: row slice
    const int lane = t & 63;
    const int h0 = lane * 8;

    __shared__ float wsm[256];
    if (t < 256) {
        const int s = s0 + t;
        const float wv = __expf(scorep[n * Sdim + s]) * sums[n];
        wsm[t] = wv;
        out_w[(size_t)s * Ndim + n] = wv;
    }
    __syncthreads();

    float4 c0 = {0.f, 0.f, 0.f, 0.f}, c1 = {0.f, 0.f, 0.f, 0.f};
#pragma unroll 4
    for (int it = 0; it < 32; ++it) {
        const int s = s0 + it * 8 + g;
        const float wv = wsm[it * 8 + g];
        const float* e = enc + ((size_t)s * Ndim + n) * Hdim + h0;
        const float4 e0 = *(const float4*)e;
        const float4 e1 = *(const float4*)(e + 4);
        c0.x += wv * e0.x; c0.y += wv * e0.y;
        c0.z += wv * e0.z; c0.w += wv * e0.w;
        c1.x += wv * e1.x; c1.y += wv * e1.y;
        c1.z += wv * e1.z; c1.w += wv * e1.w;
    }
    __shared__ __align__(16) float4 red[7][128];
    if (g > 0) { red[g - 1][lane * 2] = c0; red[g - 1][lane * 2 + 1] = c1; }
    __syncthreads();
    if (g == 0) {
#pragma unroll
        for (int i = 0; i < 7; ++i) {
            const float4 b0 = red[i][lane * 2];
            const float4 b1 = red[i][lane * 2 + 1];
            c0.x += b0.x; c0.y += b0.y; c0.z += b0.z; c0.w += b0.w;
            c1.x += b1.x; c1.y += b1.y; c1.z += b1.z; c1.w += b1.w;
        }
        float* o = part + (size_t)(sc * 32 + n) * Hdim + h0;
        *(float4*)o = c0;
        *(float4*)(o + 4) = c1;
    }
}

// ---------------- reduce 16 partial chunks -> context [N,H]
__global__ __launch_bounds__(256) void k_ctx_reduce(
    const float* __restrict__ part, float* __restrict__ out) {
    const int j = blockIdx.x * 256 + threadIdx.x;  // float4 index, 4096 total
    float4 s = {0.f, 0.f, 0.f, 0.f};
    for (int i = 0; i < 16; ++i) {
        const float4 v = ((const float4*)part)[i * 4096 + j];
        s.x += v.x; s.y += v.y; s.z += v.z; s.w += v.w;
    }
    ((float4*)out)[j] = s;
}

extern "C" void kernel_launch(void* const* d_in, const int* in_sizes, int n_in,
                              void* d_out, int out_size, void* d_ws,
                              size_t ws_size, hipStream_t stream) {
    const float* hidden = (const float*)d_in[0];
    const float* enc    = (const float*)d_in[1];
    const float* Ww     = (const float*)d_in[2];
    const float* Wb     = (const float*)d_in[3];
    const float* Uw     = (const float*)d_in[4];
    const float* Ubias  = (const float*)d_in[5];
    const float* vw     = (const float*)d_in[6];

    float* out = (float*)d_out;  // [0,16384): context; [16384,...): weights

    char* ws = (char*)d_ws;
    float* bias          = (float*)(ws);                         // 64 KB
    unsigned short* Ub16 = (unsigned short*)(ws + (64 << 10));   // 512 KB
    float* scorep        = (float*)(ws + (576 << 10));           // 512 KB
    float* sums          = (float*)(ws + (1088 << 10));          // 128 B
    float* part          = (float*)(ws + (1152 << 10));          // 1 MB

    k_prep_bias<<<128, 256, 0, stream>>>(hidden, Ww, Wb, Ubias, bias);
    k_cvt<<<256, 256, 0, stream>>>(Uw, Ub16);
    k_gemm_score<<<Mdim / BM, 512, 0, stream>>>(enc, Ub16, bias, vw, scorep);
    k_sumexp<<<Ndim, 256, 0, stream>>>(scorep, sums);
    k_context<<<Ndim * (Sdim / 256), 512, 0, stream>>>(enc, scorep, sums,
                                                       out + Ndim * Hdim, part);
    k_ctx_reduce<<<16, 256, 0, stream>>>(part, out);
}